// Round 1
// baseline (301.126 us; speedup 1.0000x reference)
//
#include <hip/hip_runtime.h>
#include <math.h>

#define D 128

__device__ __forceinline__ float softplusf(float z){
    // numerically stable softplus: log(1+e^z)
    return log1pf(expf(-fabsf(z))) + fmaxf(z, 0.f);
}

// ---- degree count ----
__global__ void k_deg(const int* __restrict__ dst, int* __restrict__ deg, int E){
    int e = blockIdx.x*blockDim.x + threadIdx.x;
    if (e < E) atomicAdd(&deg[dst[e]], 1);
}

// ---- norm = rsqrt(max(deg,1)) ----
__global__ void k_norm(const int* __restrict__ deg, float* __restrict__ norm, int N){
    int i = blockIdx.x*blockDim.x + threadIdx.x;
    if (i < N) norm[i] = rsqrtf(fmaxf((float)deg[i], 1.f));
}

// ---- block-level exclusive scan of deg -> offs, block totals -> bsum ----
__global__ void k_scanA(const int* __restrict__ deg, int* __restrict__ offs,
                        int* __restrict__ bsum, int N){
    __shared__ int s[1024];
    int tid = threadIdx.x;
    int g = blockIdx.x*1024 + tid;
    int val = (g < N) ? deg[g] : 0;
    s[tid] = val; __syncthreads();
    for (int off=1; off<1024; off<<=1){
        int t = (tid>=off) ? s[tid-off] : 0;
        __syncthreads();
        s[tid] += t;
        __syncthreads();
    }
    if (g < N) offs[g] = s[tid] - val;       // exclusive within block
    if (tid == 1023) bsum[blockIdx.x] = s[1023];
}

__global__ void k_scanB(int* __restrict__ bsum, int nb){
    if (threadIdx.x == 0){
        int acc = 0;
        for (int b=0;b<nb;b++){ int t=bsum[b]; bsum[b]=acc; acc+=t; }
    }
}

__global__ void k_scanC(int* __restrict__ offs, const int* __restrict__ bsum,
                        int* __restrict__ cursor, int N){
    int g = blockIdx.x*1024 + threadIdx.x;
    if (g < N){
        int o = offs[g] + bsum[blockIdx.x];
        offs[g] = o;
        cursor[g] = o;
    }
}

// ---- fill CSR (src ids grouped by dst) ----
__global__ void k_fill(const int* __restrict__ src, const int* __restrict__ dst,
                       int* __restrict__ cursor, int* __restrict__ csr, int E){
    int e = blockIdx.x*blockDim.x + threadIdx.x;
    if (e < E){
        int dd = dst[e];
        int p = atomicAdd(&cursor[dd], 1);
        csr[p] = src[e];
    }
}

// ---- xw = x @ W1  (W1 staged fully in LDS) ----
__global__ void __launch_bounds__(256) k_gemm(const float* __restrict__ x,
                                              const float* __restrict__ W1,
                                              float* __restrict__ xw, int N){
    __shared__ float Ws[D*D];      // 64 KiB
    __shared__ float xs[2][D];
    for (int t=threadIdx.x; t<D*D; t+=256) Ws[t] = W1[t];
    __syncthreads();
    int half = threadIdx.x >> 7;
    int d = threadIdx.x & 127;
    for (int row0 = blockIdx.x*2; row0 < N; row0 += gridDim.x*2){
        int r = row0 + half;
        if (r < N) xs[half][d] = x[r*D + d];
        __syncthreads();
        if (r < N){
            float a = 0.f;
            #pragma unroll
            for (int k=0;k<D;k++) a = fmaf(xs[half][k], Ws[k*D+d], a);
            xw[r*D + d] = a;
        }
        __syncthreads();
    }
}

// ---- precompute wps = rowsum(Wp), v = W2 @ wps, C = b2.wps + sum(bp) ----
__global__ void k_pre(const float* __restrict__ W2, const float* __restrict__ b2,
                      const float* __restrict__ Wp, const float* __restrict__ bp,
                      float* __restrict__ v, float* __restrict__ cconst){
    __shared__ float wps[D];
    __shared__ float red[D];
    int k = threadIdx.x;      // 128 threads
    float s = 0.f;
    for (int j=0;j<D;j++) s += Wp[k*D + j];
    wps[k] = s; __syncthreads();
    float vv = 0.f;
    for (int j=0;j<D;j++) vv += W2[k*D + j] * wps[j];
    v[k] = vv;
    red[k] = b2[k]*wps[k] + bp[k];
    __syncthreads();
    for (int off=64; off>0; off>>=1){ if (k<off) red[k]+=red[k+off]; __syncthreads(); }
    if (k==0) cconst[0] = red[0];
}

// ---- fused layer-1 aggregation (clean+corrupt) + relu + dot(v) -> t scalars ----
__global__ void __launch_bounds__(128) k_agg(const float* __restrict__ xw,
                     const int* __restrict__ csr, const int* __restrict__ offs,
                     const int* __restrict__ deg, const float* __restrict__ norm,
                     const int* __restrict__ perm, const float* __restrict__ b1,
                     const float* __restrict__ v, float* __restrict__ tc,
                     float* __restrict__ td, int N){
    int i = blockIdx.x;
    if (i >= N) return;
    int d = threadIdx.x;
    int start = offs[i], cnt = deg[i];
    float ac = 0.f, ad = 0.f;
    for (int k=0;k<cnt;k++){
        int s  = csr[start+k];
        float ns = norm[s];
        int sp = perm[s];
        ac = fmaf(xw[(size_t)s*D + d],  ns, ac);
        ad = fmaf(xw[(size_t)sp*D + d], ns, ad);
    }
    float ni = norm[i];
    float hc = fmaxf(fmaf(ac, ni, b1[d]), 0.f);
    float hd = fmaxf(fmaf(ad, ni, b1[d]), 0.f);
    float pc = hc * v[d];
    float pd = hd * v[d];
    // reduce 128 values (2 waves)
    for (int off=32; off>0; off>>=1){
        pc += __shfl_down(pc, off);
        pd += __shfl_down(pd, off);
    }
    __shared__ float rc[2], rd[2];
    int wid = d >> 6, lane = d & 63;
    if (lane == 0){ rc[wid] = pc; rd[wid] = pd; }
    __syncthreads();
    if (d == 0){
        tc[i] = ni * (rc[0] + rc[1]);
        td[i] = ni * (rd[0] + rd[1]);
    }
}

// ---- layer-2 scalar scatter + loss ----
__global__ void k_loss(const float* __restrict__ tc, const float* __restrict__ td,
                       const int* __restrict__ csr, const int* __restrict__ offs,
                       const int* __restrict__ deg, const float* __restrict__ norm,
                       const float* __restrict__ cconst, float* __restrict__ acc, int N){
    int i = blockIdx.x*blockDim.x + threadIdx.x;
    float li = 0.f;
    if (i < N){
        int start = offs[i], cnt = deg[i];
        float sc = 0.f, sd = 0.f;
        for (int k=0;k<cnt;k++){
            int s = csr[start+k];
            sc += tc[s];
            sd += td[s];
        }
        float ni = norm[i], C = cconst[0];
        float z1 = fmaf(ni, sc, C);   // clean logit (label 1)
        float z2 = fmaf(ni, sd, C);   // corrupt logit (label 0)
        li = softplusf(-z1) + softplusf(z2);
    }
    for (int off=32; off>0; off>>=1) li += __shfl_down(li, off);
    __shared__ float w[4];
    int lane = threadIdx.x & 63, wid = threadIdx.x >> 6;
    if (lane == 0) w[wid] = li;
    __syncthreads();
    if (threadIdx.x == 0){
        float s = 0.f;
        int nw = blockDim.x >> 6;
        for (int q=0;q<nw;q++) s += w[q];
        atomicAdd(acc, s);
    }
}

__global__ void k_final(const float* __restrict__ acc, float* __restrict__ out, int N){
    if (threadIdx.x == 0) out[0] = acc[0] / (float)(2*N);
}

extern "C" void kernel_launch(void* const* d_in, const int* in_sizes, int n_in,
                              void* d_out, int out_size, void* d_ws, size_t ws_size,
                              hipStream_t stream){
    const float* x    = (const float*)d_in[0];
    const float* W1   = (const float*)d_in[1];
    const float* b1   = (const float*)d_in[2];
    const float* W2   = (const float*)d_in[3];
    const float* b2   = (const float*)d_in[4];
    const float* Wp   = (const float*)d_in[5];
    const float* bp   = (const float*)d_in[6];
    const int*   esrc = (const int*)d_in[7];
    const int*   edst = (const int*)d_in[8];
    const int*   perm = (const int*)d_in[9];
    const int N = in_sizes[0] / D;
    const int E = in_sizes[7];

    char* ws = (char*)d_ws;
    size_t off = 0;
    auto alloc = [&](size_t bytes)->void*{
        void* p = ws + off;
        off += (bytes + 255) & ~(size_t)255;
        return p;
    };
    float* xw     = (float*)alloc((size_t)N*D*sizeof(float));
    int*   deg    = (int*)  alloc((size_t)N*sizeof(int));
    float* norm   = (float*)alloc((size_t)N*sizeof(float));
    int*   offs   = (int*)  alloc((size_t)N*sizeof(int));
    int*   cursor = (int*)  alloc((size_t)N*sizeof(int));
    int*   csr    = (int*)  alloc((size_t)E*sizeof(int));
    float* tc     = (float*)alloc((size_t)N*sizeof(float));
    float* td     = (float*)alloc((size_t)N*sizeof(float));
    int*   bsum   = (int*)  alloc(1024);
    float* v      = (float*)alloc(D*sizeof(float));
    float* cconst = (float*)alloc(sizeof(float));
    float* acc    = (float*)alloc(sizeof(float));

    hipMemsetAsync(deg, 0, (size_t)N*sizeof(int), stream);
    hipMemsetAsync(acc, 0, sizeof(float), stream);

    int nb = (N + 1023) / 1024;
    k_deg <<<(E+255)/256, 256, 0, stream>>>(edst, deg, E);
    k_norm<<<(N+255)/256, 256, 0, stream>>>(deg, norm, N);
    k_scanA<<<nb, 1024, 0, stream>>>(deg, offs, bsum, N);
    k_scanB<<<1, 64, 0, stream>>>(bsum, nb);
    k_scanC<<<nb, 1024, 0, stream>>>(offs, bsum, cursor, N);
    k_fill<<<(E+255)/256, 256, 0, stream>>>(esrc, edst, cursor, csr, E);
    k_gemm<<<512, 256, 0, stream>>>(x, W1, xw, N);
    k_pre<<<1, D, 0, stream>>>(W2, b2, Wp, bp, v, cconst);
    k_agg<<<N, D, 0, stream>>>(xw, csr, offs, deg, norm, perm, b1, v, tc, td, N);
    k_loss<<<(N+255)/256, 256, 0, stream>>>(tc, td, csr, offs, deg, norm, cconst, acc, N);
    k_final<<<1, 1, 0, stream>>>(acc, (float*)d_out, N);
}

// Round 2
// 212.444 us; speedup vs baseline: 1.4174x; 1.4174x over previous
//
#include <hip/hip_runtime.h>
#include <math.h>

#define D 128

__device__ __forceinline__ float softplusf(float z){
    return log1pf(expf(-fabsf(z))) + fmaxf(z, 0.f);
}

// ---- degree count ----
__global__ void k_deg(const int* __restrict__ dst, int* __restrict__ deg, int E){
    int e = blockIdx.x*blockDim.x + threadIdx.x;
    if (e < E) atomicAdd(&deg[dst[e]], 1);
}

// ---- block-level exclusive scan of deg -> offs, block totals -> bsum ----
__global__ void k_scanA(const int* __restrict__ deg, int* __restrict__ offs,
                        int* __restrict__ bsum, int N){
    __shared__ int s[1024];
    int tid = threadIdx.x;
    int g = blockIdx.x*1024 + tid;
    int val = (g < N) ? deg[g] : 0;
    s[tid] = val; __syncthreads();
    for (int off=1; off<1024; off<<=1){
        int t = (tid>=off) ? s[tid-off] : 0;
        __syncthreads();
        s[tid] += t;
        __syncthreads();
    }
    if (g < N) offs[g] = s[tid] - val;       // exclusive within block
    if (tid == 1023) bsum[blockIdx.x] = s[1023];
}

// ---- parallel exclusive scan of block sums (nb <= 1024) ----
__global__ void k_scanB(int* __restrict__ bsum, int nb){
    __shared__ int s[1024];
    int t = threadIdx.x;
    int v = (t < nb) ? bsum[t] : 0;
    s[t] = v; __syncthreads();
    for (int off=1; off<1024; off<<=1){
        int tv = (t>=off) ? s[t-off] : 0;
        __syncthreads();
        s[t] += tv;
        __syncthreads();
    }
    if (t < nb) bsum[t] = s[t] - v;          // exclusive
}

// ---- finalize offsets + cursor + norm ----
__global__ void k_scanC(int* __restrict__ offs, const int* __restrict__ bsum,
                        int* __restrict__ cursor, const int* __restrict__ deg,
                        float* __restrict__ norm, int N){
    int g = blockIdx.x*1024 + threadIdx.x;
    if (g < N){
        int o = offs[g] + bsum[blockIdx.x];
        offs[g] = o;
        cursor[g] = o;
        norm[g] = rsqrtf(fmaxf((float)deg[g], 1.f));
    }
}

// ---- fill CSR (src ids grouped by dst) ----
__global__ void k_fill(const int* __restrict__ src, const int* __restrict__ dst,
                       int* __restrict__ cursor, int* __restrict__ csr, int E){
    int e = blockIdx.x*blockDim.x + threadIdx.x;
    if (e < E){
        int dd = dst[e];
        int p = atomicAdd(&cursor[dd], 1);
        csr[p] = src[e];
    }
}

// ---- xw = x @ W1 : 32-row tiles, 32-k LDS panels, 4x4 register tile ----
__global__ void __launch_bounds__(256) k_gemm(const float* __restrict__ x,
                                              const float* __restrict__ W1,
                                              float* __restrict__ xw, int N){
    __shared__ float Ws[32*D];     // 16 KB k-panel of W (32 k x 128 cols)
    __shared__ float xs[32][36];   // 32 rows x 32 k (+pad)
    const int tid = threadIdx.x;
    const int cg  = tid & 31;      // col group -> cols 4cg..4cg+3
    const int rg  = tid >> 5;      // row group -> rows rg*4..rg*4+3
    int row0 = blockIdx.x * 32;
    float4 acc[4];
    #pragma unroll
    for (int q=0;q<4;q++) acc[q] = make_float4(0.f,0.f,0.f,0.f);

    for (int p = 0; p < 4; ++p){
        int k0 = p*32;
        // load W panel (4096 floats)
        {
            int r = tid >> 5;
            int c = (tid & 31) * 4;
            #pragma unroll
            for (int s2 = 0; s2 < 4; ++s2){
                int kk = r + s2*8;
                *(float4*)&Ws[kk*D + c] = *(const float4*)&W1[(size_t)(k0+kk)*D + c];
            }
        }
        // load x panel (32 rows x 32 floats)
        {
            int rr = tid >> 3;
            int cc = (tid & 7) * 4;
            int grow = row0 + rr;
            float4 vx = make_float4(0.f,0.f,0.f,0.f);
            if (grow < N) vx = *(const float4*)&x[(size_t)grow*D + k0 + cc];
            *(float4*)&xs[rr][cc] = vx;
        }
        __syncthreads();
        #pragma unroll
        for (int kk = 0; kk < 32; ++kk){
            float4 w = *(const float4*)&Ws[kk*D + cg*4];
            #pragma unroll
            for (int q = 0; q < 4; ++q){
                float xv = xs[rg*4 + q][kk];
                acc[q].x = fmaf(xv, w.x, acc[q].x);
                acc[q].y = fmaf(xv, w.y, acc[q].y);
                acc[q].z = fmaf(xv, w.z, acc[q].z);
                acc[q].w = fmaf(xv, w.w, acc[q].w);
            }
        }
        __syncthreads();
    }
    #pragma unroll
    for (int q = 0; q < 4; ++q){
        int r = row0 + rg*4 + q;
        if (r < N) *(float4*)&xw[(size_t)r*D + cg*4] = acc[q];
    }
}

// ---- precompute wps = rowsum(Wp), v = W2 @ wps, C = b2.wps + sum(bp) ----
__global__ void __launch_bounds__(256) k_pre(const float* __restrict__ W2, const float* __restrict__ b2,
                      const float* __restrict__ Wp, const float* __restrict__ bp,
                      float* __restrict__ v, float* __restrict__ cconst){
    __shared__ float M[D*D];       // 64 KB staging
    __shared__ float wps[D];
    __shared__ float red[D];
    int tid = threadIdx.x;
    for (int t = tid; t < D*D/4; t += 256) ((float4*)M)[t] = ((const float4*)Wp)[t];
    __syncthreads();
    if (tid < D){
        float sum = 0.f;
        for (int j = 0; j < D; ++j){
            int jj = (j + tid) & (D-1);        // rotated -> conflict-free
            sum += M[tid*D + jj];
        }
        wps[tid] = sum;
    }
    __syncthreads();
    for (int t = tid; t < D*D/4; t += 256) ((float4*)M)[t] = ((const float4*)W2)[t];
    __syncthreads();
    if (tid < D){
        float sum = 0.f;
        for (int j = 0; j < D; ++j){
            int jj = (j + tid) & (D-1);
            sum += M[tid*D + jj] * wps[jj];
        }
        v[tid] = sum;
        red[tid] = b2[tid]*wps[tid] + bp[tid];
    }
    __syncthreads();
    if (tid < 64) red[tid] += red[tid+64];
    __syncthreads();
    if (tid < 64){
        float r = red[tid];
        for (int off=32; off>0; off>>=1) r += __shfl_down(r, off);
        if (tid==0) cconst[0] = r;
    }
}

// ---- fused layer-1 aggregation (clean+corrupt) + relu + dot(v) ----
// one wave per node; batched index prefetch; float4 gathers, 2 neighbors/wave-instr
__global__ void __launch_bounds__(256) k_agg(const float* __restrict__ xw,
                     const int* __restrict__ csr, const int* __restrict__ offs,
                     const int* __restrict__ deg, const float* __restrict__ norm,
                     const int* __restrict__ perm, const float* __restrict__ b1,
                     const float* __restrict__ v, float* __restrict__ tc,
                     float* __restrict__ td, int N){
    int w = threadIdx.x >> 6;
    int lane = threadIdx.x & 63;
    int i = blockIdx.x*4 + w;
    if (i >= N) return;
    int half = lane >> 5;              // which neighbor of the pair
    int c4   = lane & 31;              // float4 column group
    const float4* __restrict__ xw4 = (const float4*)xw;   // row stride 32
    float4 ac = make_float4(0.f,0.f,0.f,0.f);
    float4 ad = make_float4(0.f,0.f,0.f,0.f);
    int start = offs[i], cnt = deg[i];

    for (int base = 0; base < cnt; base += 64){
        int m = min(cnt - base, 64);
        int s = 0; float ns = 0.f; int sp = 0;
        if (lane < m){
            s  = csr[start + base + lane];
            ns = norm[s];
            sp = perm[s];
        }
        for (int k = 0; k < m; k += 2){
            int k2 = k + half;
            int kk = (k2 < m) ? k2 : k;          // clamp odd tail
            int   sk  = __shfl(s,  kk);
            int   spk = __shfl(sp, kk);
            float nsk = __shfl(ns, kk);
            float nk  = (k2 < m) ? nsk : 0.f;
            float4 va = xw4[(size_t)sk*32  + c4];
            float4 vb = xw4[(size_t)spk*32 + c4];
            ac.x = fmaf(va.x, nk, ac.x); ac.y = fmaf(va.y, nk, ac.y);
            ac.z = fmaf(va.z, nk, ac.z); ac.w = fmaf(va.w, nk, ac.w);
            ad.x = fmaf(vb.x, nk, ad.x); ad.y = fmaf(vb.y, nk, ad.y);
            ad.z = fmaf(vb.z, nk, ad.z); ad.w = fmaf(vb.w, nk, ad.w);
        }
    }
    // combine half-wave partials (both halves map c4 -> same columns)
    ac.x += __shfl_xor(ac.x, 32); ac.y += __shfl_xor(ac.y, 32);
    ac.z += __shfl_xor(ac.z, 32); ac.w += __shfl_xor(ac.w, 32);
    ad.x += __shfl_xor(ad.x, 32); ad.y += __shfl_xor(ad.y, 32);
    ad.z += __shfl_xor(ad.z, 32); ad.w += __shfl_xor(ad.w, 32);

    float ni = norm[i];
    float4 bb = ((const float4*)b1)[c4];
    float4 vv = ((const float4*)v)[c4];
    float pc = fmaxf(fmaf(ac.x, ni, bb.x), 0.f)*vv.x
             + fmaxf(fmaf(ac.y, ni, bb.y), 0.f)*vv.y
             + fmaxf(fmaf(ac.z, ni, bb.z), 0.f)*vv.z
             + fmaxf(fmaf(ac.w, ni, bb.w), 0.f)*vv.w;
    float pd = fmaxf(fmaf(ad.x, ni, bb.x), 0.f)*vv.x
             + fmaxf(fmaf(ad.y, ni, bb.y), 0.f)*vv.y
             + fmaxf(fmaf(ad.z, ni, bb.z), 0.f)*vv.z
             + fmaxf(fmaf(ad.w, ni, bb.w), 0.f)*vv.w;
    for (int off=16; off>0; off>>=1){
        pc += __shfl_xor(pc, off);
        pd += __shfl_xor(pd, off);
    }
    if (lane == 0){
        tc[i] = ni * pc;
        td[i] = ni * pd;
    }
}

// ---- layer-2 scalar scatter + loss ----
__global__ void k_loss(const float* __restrict__ tc, const float* __restrict__ td,
                       const int* __restrict__ csr, const int* __restrict__ offs,
                       const int* __restrict__ deg, const float* __restrict__ norm,
                       const float* __restrict__ cconst, float* __restrict__ acc, int N){
    int i = blockIdx.x*blockDim.x + threadIdx.x;
    float li = 0.f;
    if (i < N){
        int start = offs[i], cnt = deg[i];
        float sc = 0.f, sd = 0.f;
        for (int k=0;k<cnt;k++){
            int s = csr[start+k];
            sc += tc[s];
            sd += td[s];
        }
        float ni = norm[i], C = cconst[0];
        float z1 = fmaf(ni, sc, C);
        float z2 = fmaf(ni, sd, C);
        li = softplusf(-z1) + softplusf(z2);
    }
    for (int off=32; off>0; off>>=1) li += __shfl_down(li, off);
    __shared__ float wsum[4];
    int lane = threadIdx.x & 63, wid = threadIdx.x >> 6;
    if (lane == 0) wsum[wid] = li;
    __syncthreads();
    if (threadIdx.x == 0){
        float s = 0.f;
        int nw = blockDim.x >> 6;
        for (int q=0;q<nw;q++) s += wsum[q];
        atomicAdd(acc, s);
    }
}

__global__ void k_final(const float* __restrict__ acc, float* __restrict__ out, int N){
    if (threadIdx.x == 0) out[0] = acc[0] / (float)(2*N);
}

extern "C" void kernel_launch(void* const* d_in, const int* in_sizes, int n_in,
                              void* d_out, int out_size, void* d_ws, size_t ws_size,
                              hipStream_t stream){
    const float* x    = (const float*)d_in[0];
    const float* W1   = (const float*)d_in[1];
    const float* b1   = (const float*)d_in[2];
    const float* W2   = (const float*)d_in[3];
    const float* b2   = (const float*)d_in[4];
    const float* Wp   = (const float*)d_in[5];
    const float* bp   = (const float*)d_in[6];
    const int*   esrc = (const int*)d_in[7];
    const int*   edst = (const int*)d_in[8];
    const int*   perm = (const int*)d_in[9];
    const int N = in_sizes[0] / D;
    const int E = in_sizes[7];

    char* ws = (char*)d_ws;
    size_t off = 0;
    auto alloc = [&](size_t bytes)->void*{
        void* p = ws + off;
        off += (bytes + 255) & ~(size_t)255;
        return p;
    };
    float* xw     = (float*)alloc((size_t)N*D*sizeof(float));
    int*   deg    = (int*)  alloc((size_t)N*sizeof(int));
    float* norm   = (float*)alloc((size_t)N*sizeof(float));
    int*   offs   = (int*)  alloc((size_t)N*sizeof(int));
    int*   cursor = (int*)  alloc((size_t)N*sizeof(int));
    int*   csr    = (int*)  alloc((size_t)E*sizeof(int));
    float* tc     = (float*)alloc((size_t)N*sizeof(float));
    float* td     = (float*)alloc((size_t)N*sizeof(float));
    int*   bsum   = (int*)  alloc(4096);
    float* v      = (float*)alloc(D*sizeof(float));
    float* cconst = (float*)alloc(sizeof(float));
    float* acc    = (float*)alloc(sizeof(float));

    hipMemsetAsync(deg, 0, (size_t)N*sizeof(int), stream);
    hipMemsetAsync(acc, 0, sizeof(float), stream);

    int nb = (N + 1023) / 1024;
    k_deg  <<<(E+255)/256, 256, 0, stream>>>(edst, deg, E);
    k_scanA<<<nb, 1024, 0, stream>>>(deg, offs, bsum, N);
    k_scanB<<<1, 1024, 0, stream>>>(bsum, nb);
    k_scanC<<<nb, 1024, 0, stream>>>(offs, bsum, cursor, deg, norm, N);
    k_fill <<<(E+255)/256, 256, 0, stream>>>(esrc, edst, cursor, csr, E);
    k_gemm <<<(N+31)/32, 256, 0, stream>>>(x, W1, xw, N);
    k_pre  <<<1, 256, 0, stream>>>(W2, b2, Wp, bp, v, cconst);
    k_agg  <<<(N+3)/4, 256, 0, stream>>>(xw, csr, offs, deg, norm, perm, b1, v, tc, td, N);
    k_loss <<<(N+255)/256, 256, 0, stream>>>(tc, td, csr, offs, deg, norm, cconst, acc, N);
    k_final<<<1, 1, 0, stream>>>(acc, (float*)d_out, N);
}

// Round 3
// 143.460 us; speedup vs baseline: 2.0990x; 1.4809x over previous
//
#include <hip/hip_runtime.h>
#include <math.h>

#define D 128

__device__ __forceinline__ float softplusf(float z){
    return log1pf(expf(-fabsf(z))) + fmaxf(z, 0.f);
}
__device__ __forceinline__ unsigned short f2bf(float f){
    unsigned u = __float_as_uint(f);
    u += 0x7fffu + ((u >> 16) & 1u);          // round-to-nearest-even
    return (unsigned short)(u >> 16);
}

// ---- fused: xw16 = bf16(x @ W1)  |  deg count  |  pre (v, cconst) ----
__global__ void __launch_bounds__(256) k_fused1(
    const float* __restrict__ x, const float* __restrict__ W1,
    unsigned short* __restrict__ xw16, int N,
    const int* __restrict__ edst, int* __restrict__ deg, int E,
    int nGemm, int nDeg,
    const float* __restrict__ W2, const float* __restrict__ b2,
    const float* __restrict__ Wp, const float* __restrict__ bp,
    float* __restrict__ v, float* __restrict__ cconst)
{
    __shared__ float smem[32*D + 32*36];
    const int b = blockIdx.x;
    const int tid = threadIdx.x;
    if (b < nGemm){
        float* Ws = smem;                                   // 32 k x 128
        float (*xs)[36] = (float(*)[36])(smem + 32*D);      // 32 rows x 32 k
        const int cg = tid & 31;
        const int rg = tid >> 5;
        int row0 = b * 32;
        float4 acc[4];
        #pragma unroll
        for (int q=0;q<4;q++) acc[q] = make_float4(0.f,0.f,0.f,0.f);
        for (int p = 0; p < 4; ++p){
            int k0 = p*32;
            {
                int r = tid >> 5;
                int c = (tid & 31) * 4;
                #pragma unroll
                for (int s2 = 0; s2 < 4; ++s2){
                    int kk = r + s2*8;
                    *(float4*)&Ws[kk*D + c] = *(const float4*)&W1[(size_t)(k0+kk)*D + c];
                }
            }
            {
                int rr = tid >> 3;
                int cc = (tid & 7) * 4;
                int grow = row0 + rr;
                float4 vx = make_float4(0.f,0.f,0.f,0.f);
                if (grow < N) vx = *(const float4*)&x[(size_t)grow*D + k0 + cc];
                *(float4*)&xs[rr][cc] = vx;
            }
            __syncthreads();
            #pragma unroll
            for (int kk = 0; kk < 32; ++kk){
                float4 w = *(const float4*)&Ws[kk*D + cg*4];
                #pragma unroll
                for (int q = 0; q < 4; ++q){
                    float xv = xs[rg*4 + q][kk];
                    acc[q].x = fmaf(xv, w.x, acc[q].x);
                    acc[q].y = fmaf(xv, w.y, acc[q].y);
                    acc[q].z = fmaf(xv, w.z, acc[q].z);
                    acc[q].w = fmaf(xv, w.w, acc[q].w);
                }
            }
            __syncthreads();
        }
        #pragma unroll
        for (int q = 0; q < 4; ++q){
            int r = row0 + rg*4 + q;
            if (r < N){
                ushort4 o;
                o.x = f2bf(acc[q].x); o.y = f2bf(acc[q].y);
                o.z = f2bf(acc[q].z); o.w = f2bf(acc[q].w);
                *(ushort4*)&xw16[(size_t)r*D + cg*4] = o;
            }
        }
    } else if (b < nGemm + nDeg){
        int e = (b - nGemm)*256 + tid;
        if (e < E) atomicAdd(&deg[edst[e]], 1);
    } else {
        float* wps = smem;
        float* red = smem + D;
        if (tid < D){
            float s = 0.f;
            for (int j = 0; j < D; ++j) s += Wp[(size_t)tid*D + j];
            wps[tid] = s;
        }
        __syncthreads();
        if (tid < D){
            float vv = 0.f;
            for (int j = 0; j < D; ++j) vv += W2[(size_t)tid*D + j] * wps[j];
            v[tid] = vv;
            red[tid] = b2[tid]*wps[tid] + bp[tid];
        }
        __syncthreads();
        if (tid < 64) red[tid] += red[tid+64];
        __syncthreads();
        if (tid < 64){
            float r = red[tid];
            for (int off=32; off>0; off>>=1) r += __shfl_down(r, off);
            if (tid==0) cconst[0] = r;
        }
    }
}

// ---- block-level exclusive scan of deg -> offs, block totals -> bsum ----
__global__ void k_scanA(const int* __restrict__ deg, int* __restrict__ offs,
                        int* __restrict__ bsum, int N){
    __shared__ int s[1024];
    int tid = threadIdx.x;
    int g = blockIdx.x*1024 + tid;
    int val = (g < N) ? deg[g] : 0;
    s[tid] = val; __syncthreads();
    for (int off=1; off<1024; off<<=1){
        int t = (tid>=off) ? s[tid-off] : 0;
        __syncthreads();
        s[tid] += t;
        __syncthreads();
    }
    if (g < N) offs[g] = s[tid] - val;
    if (tid == 1023) bsum[blockIdx.x] = s[1023];
}

// ---- finalize: cross-block prefix (nb<=64), offs, cursor, norm, ep ----
__global__ void k_scanC(int* __restrict__ offs, const int* __restrict__ bsum,
                        int* __restrict__ cursor, const int* __restrict__ deg,
                        float* __restrict__ norm, int2* __restrict__ ep,
                        const int* __restrict__ perm, int N){
    __shared__ int sbase;
    int tid = threadIdx.x;
    if (tid < 64){
        int val = (tid < (int)blockIdx.x) ? bsum[tid] : 0;
        for (int off=32; off>0; off>>=1) val += __shfl_down(val, off);
        if (tid == 0) sbase = val;
    }
    __syncthreads();
    int g = blockIdx.x*1024 + tid;
    if (g < N){
        int o = offs[g] + sbase;
        offs[g] = o;
        cursor[g] = o;
        float nm = rsqrtf(fmaxf((float)deg[g], 1.f));
        norm[g] = nm;
        ep[g] = make_int2(perm[g], __float_as_int(nm));
    }
}

// ---- fill CSR (src ids grouped by dst, uint16) ----
__global__ void k_fill(const int* __restrict__ src, const int* __restrict__ dst,
                       int* __restrict__ cursor, unsigned short* __restrict__ csr, int E){
    int e = blockIdx.x*blockDim.x + threadIdx.x;
    if (e < E){
        int dd = dst[e];
        int p = atomicAdd(&cursor[dd], 1);
        csr[p] = (unsigned short)src[e];
    }
}

#define FMA4(dv, nk) \
    ac.x = fmaf(__uint_as_float((dv).x << 16),          (nk), ac.x); \
    ac.y = fmaf(__uint_as_float((dv).x & 0xffff0000u),  (nk), ac.y); \
    ac.z = fmaf(__uint_as_float((dv).y << 16),          (nk), ac.z); \
    ac.w = fmaf(__uint_as_float((dv).y & 0xffff0000u),  (nk), ac.w);

// ---- fused layer-1 agg (clean on lanes 0-31, corrupt on 32-63) + relu + dot(v) ----
__global__ void __launch_bounds__(256) k_agg(const unsigned short* __restrict__ xw16,
                     const unsigned short* __restrict__ csr, const int* __restrict__ offs,
                     const int* __restrict__ deg, const float* __restrict__ norm,
                     const int2* __restrict__ ep, const float* __restrict__ b1,
                     const float* __restrict__ v, float2* __restrict__ t2, int N){
    int w = threadIdx.x >> 6;
    int lane = threadIdx.x & 63;
    int i = blockIdx.x*4 + w;
    if (i >= N) return;
    int half = lane >> 5;
    int c = lane & 31;
    const uint2* __restrict__ xr = (const uint2*)xw16;    // row stride 32 uint2 (256B)
    float4 ac = make_float4(0.f,0.f,0.f,0.f);
    int start = offs[i], cnt = deg[i];

    for (int base = 0; base < cnt; base += 64){
        int m = min(cnt - base, 64);
        int s = 0, sp = 0; float ns = 0.f;
        if (lane < m){
            s = csr[start + base + lane];
            int2 e = ep[s];
            sp = e.x; ns = __int_as_float(e.y);
        }
        int k = 0;
        for (; k + 4 <= m; k += 4){
            int ra0=__shfl(s,k  ), rb0=__shfl(sp,k  ); float n0=__shfl(ns,k  );
            int ra1=__shfl(s,k+1), rb1=__shfl(sp,k+1); float n1=__shfl(ns,k+1);
            int ra2=__shfl(s,k+2), rb2=__shfl(sp,k+2); float n2=__shfl(ns,k+2);
            int ra3=__shfl(s,k+3), rb3=__shfl(sp,k+3); float n3=__shfl(ns,k+3);
            int r0 = half ? rb0 : ra0;
            int r1 = half ? rb1 : ra1;
            int r2 = half ? rb2 : ra2;
            int r3 = half ? rb3 : ra3;
            uint2 d0 = xr[(size_t)r0*32 + c];
            uint2 d1 = xr[(size_t)r1*32 + c];
            uint2 d2 = xr[(size_t)r2*32 + c];
            uint2 d3 = xr[(size_t)r3*32 + c];
            FMA4(d0, n0); FMA4(d1, n1); FMA4(d2, n2); FMA4(d3, n3);
        }
        for (; k < m; ++k){
            int ra=__shfl(s,k), rb=__shfl(sp,k); float nk=__shfl(ns,k);
            int r = half ? rb : ra;
            uint2 dv = xr[(size_t)r*32 + c];
            FMA4(dv, nk);
        }
    }
    float ni = norm[i];
    float4 bb = ((const float4*)b1)[c];
    float4 vv = ((const float4*)v)[c];
    float p = fmaxf(fmaf(ac.x, ni, bb.x), 0.f)*vv.x
            + fmaxf(fmaf(ac.y, ni, bb.y), 0.f)*vv.y
            + fmaxf(fmaf(ac.z, ni, bb.z), 0.f)*vv.z
            + fmaxf(fmaf(ac.w, ni, bb.w), 0.f)*vv.w;
    for (int off=16; off>0; off>>=1) p += __shfl_xor(p, off);
    float pd = __shfl(p, 32);
    if (lane == 0) t2[i] = make_float2(ni*p, ni*pd);
}

// ---- layer-2 scalar gather + loss + final (last-block) ----
__global__ void k_loss(const float2* __restrict__ t2, const unsigned short* __restrict__ csr,
                       const int* __restrict__ offs, const int* __restrict__ deg,
                       const float* __restrict__ norm, const float* __restrict__ cconst,
                       float* __restrict__ acc, unsigned* __restrict__ done,
                       float* __restrict__ out, int N, int nblocks){
    int i = blockIdx.x*blockDim.x + threadIdx.x;
    float li = 0.f;
    if (i < N){
        int start = offs[i], cnt = deg[i];
        float sc = 0.f, sd = 0.f;
        for (int k=0;k<cnt;k++){
            int s = csr[start+k];
            float2 t = t2[s];
            sc += t.x; sd += t.y;
        }
        float ni = norm[i], C = cconst[0];
        li = softplusf(-fmaf(ni, sc, C)) + softplusf(fmaf(ni, sd, C));
    }
    for (int off=32; off>0; off>>=1) li += __shfl_down(li, off);
    __shared__ float wsum[4];
    int lane = threadIdx.x & 63, wid = threadIdx.x >> 6;
    if (lane == 0) wsum[wid] = li;
    __syncthreads();
    if (threadIdx.x == 0){
        float s = wsum[0] + wsum[1] + wsum[2] + wsum[3];
        atomicAdd(acc, s);
        __threadfence();
        unsigned t = atomicAdd(done, 1u);
        if (t == (unsigned)(nblocks - 1)){
            float tot = atomicAdd(acc, 0.0f);      // returns final sum
            out[0] = tot / (float)(2*N);
        }
    }
}

extern "C" void kernel_launch(void* const* d_in, const int* in_sizes, int n_in,
                              void* d_out, int out_size, void* d_ws, size_t ws_size,
                              hipStream_t stream){
    const float* x    = (const float*)d_in[0];
    const float* W1   = (const float*)d_in[1];
    const float* b1   = (const float*)d_in[2];
    const float* W2   = (const float*)d_in[3];
    const float* b2   = (const float*)d_in[4];
    const float* Wp   = (const float*)d_in[5];
    const float* bp   = (const float*)d_in[6];
    const int*   esrc = (const int*)d_in[7];
    const int*   edst = (const int*)d_in[8];
    const int*   perm = (const int*)d_in[9];
    const int N = in_sizes[0] / D;
    const int E = in_sizes[7];

    char* ws = (char*)d_ws;
    size_t off = 0;
    auto alloc = [&](size_t bytes)->void*{
        void* p = ws + off;
        off += (bytes + 255) & ~(size_t)255;
        return p;
    };
    unsigned short* xw16 = (unsigned short*)alloc((size_t)N*D*sizeof(unsigned short));
    int*   deg    = (int*)  alloc((size_t)N*sizeof(int));
    float* norm   = (float*)alloc((size_t)N*sizeof(float));
    int*   offs   = (int*)  alloc((size_t)N*sizeof(int));
    int*   cursor = (int*)  alloc((size_t)N*sizeof(int));
    int2*  ep     = (int2*) alloc((size_t)N*sizeof(int2));
    unsigned short* csr = (unsigned short*)alloc((size_t)E*sizeof(unsigned short));
    float2* t2    = (float2*)alloc((size_t)N*sizeof(float2));
    int*   bsum   = (int*)  alloc(4096);
    float* v      = (float*)alloc(D*sizeof(float));
    float* cconst = (float*)alloc(256);
    float* acc    = (float*)alloc(256);
    unsigned* done = (unsigned*)(acc + 1);

    hipMemsetAsync(deg, 0, (size_t)N*sizeof(int), stream);
    hipMemsetAsync(acc, 0, 256, stream);

    int nGemm = (N + 31) / 32;
    int nDeg  = (E + 255) / 256;
    int nb    = (N + 1023) / 1024;
    int nLoss = (N + 255) / 256;

    k_fused1<<<nGemm + nDeg + 1, 256, 0, stream>>>(x, W1, xw16, N, edst, deg, E,
                                                   nGemm, nDeg, W2, b2, Wp, bp, v, cconst);
    k_scanA<<<nb, 1024, 0, stream>>>(deg, offs, bsum, N);
    k_scanC<<<nb, 1024, 0, stream>>>(offs, bsum, cursor, deg, norm, ep, perm, N);
    k_fill <<<(E+255)/256, 256, 0, stream>>>(esrc, edst, cursor, csr, E);
    k_agg  <<<(N+3)/4, 256, 0, stream>>>(xw16, csr, offs, deg, norm, ep, b1, v, t2, N);
    k_loss <<<nLoss, 256, 0, stream>>>(t2, csr, offs, deg, norm, cconst, acc, done,
                                       (float*)d_out, N, nLoss);
}